// Round 2
// baseline (57615.454 us; speedup 1.0000x reference)
//
#include <hip/hip_runtime.h>

typedef _Float16 f16;
typedef _Float16 half8 __attribute__((ext_vector_type(8)));
typedef _Float16 half4 __attribute__((ext_vector_type(4)));
typedef float float4v __attribute__((ext_vector_type(4)));
typedef unsigned int u32;

constexpr int NB = 128;      // persistent blocks (64 L0 + 64 L1)
constexpr int NT = 256;      // threads per block (4 waves)
constexpr int HD = 512;      // hidden size
constexpr int NBAT = 64;     // batch
constexpr int DIN = 176;     // input feature dim
constexpr int KXPAD = 192;   // padded input dim (176 -> 192, multiple of 32)
constexpr int TENC = 1025;   // encoder steps
constexpr int TDEC = 1023;   // decoder steps
constexpr int STOT = 2050;   // total global steps (enc 1026 + dec 1024)

// ---- ws layout (bytes) ----
constexpr size_t WS_CNT = 0;          // counters (4 KB)
constexpr size_t WS_H0  = 4096;       // h0 [2][64][512] f16  (128 KB)
constexpr size_t WS_H1  = 135168;     // h1 [2][64][512] f16  (128 KB)
constexpr size_t WS_ZERO_END = 266240;
constexpr size_t WS_XH  = 266240;     // xh [1025][64][192] f16
constexpr size_t WS_DH  = 25456640;   // dh [1023][64][192] f16
constexpr size_t WS_HS  = 50597888;   // hs [1023][64][512] f16
constexpr size_t WS_W1  = 117641216;  // W1h [256][512] f16
constexpr size_t WS_W2  = 117903360;  // W2h [176][256] f16
constexpr size_t WS_END = 117993472;

__device__ __forceinline__ float sigf(float x){ return 1.f/(1.f + __expf(-x)); }
__device__ __forceinline__ float tanhf_(float x){ return 2.f/(1.f + __expf(-2.f*x)) - 1.f; }

__device__ __forceinline__ float4v mfma16(half8 a, half8 b, float4v c){
  return __builtin_amdgcn_mfma_f32_16x16x32_f16(a, b, c, 0, 0, 0);
}

struct Params {
  const float* W_i[2][2];  // [phase][layer] input-weight (4H x din)
  const float* W_h[2][2];  // recurrent weight (4H x 512)
  const float* b_i[2][2];
  const float* b_h[2][2];
  f16* xh; f16* dh; f16* h0; f16* h1; f16* hs;
  u32* cnt;
};

// Load this block's weight slice into LDS in MFMA-fragment-major layout.
// Slot idx = (mt*KC + kc)*64 + lane ; each slot = 8 f16 (row = lane&15 within
// M-tile, k = kc*32 + (lane>>4)*8 + j).  M-tile0 rows = [i(cb..cb+7), f(..)],
// M-tile1 = [g, o].
__device__ void load_weights(const float* Wi, const float* Wh, int KC, int KX,
                             int SI, int cb, f16* wlds){
  __syncthreads();
  const int slots = 2*KC*64;
  for (int idx = threadIdx.x; idx < slots; idx += NT){
    int mt = idx / (KC*64);
    int rem = idx - mt*(KC*64);
    int kc = rem >> 6;
    int l = rem & 63;
    int r = l & 15;
    int kgg = l >> 4;
    int grow;
    if (mt==0) grow = (r<8) ? (cb + r) : (512 + cb + (r-8));
    else       grow = (r<8) ? (1024 + cb + r) : (1536 + cb + (r-8));
    int k0 = kc*32 + kgg*8;
    f16* dst = wlds + (size_t)idx*8;
    #pragma unroll
    for (int j=0;j<8;j++){
      int k = k0 + j;
      float v;
      if (k < KX) v = (k < SI) ? Wi[(size_t)grow*SI + k] : 0.f;
      else        v = Wh[(size_t)grow*HD + (k - KX)];
      dst[j] = (f16)v;
    }
  }
  __syncthreads();
}

__device__ void load_bias(const float* bi, const float* bh, int cb, int q,
                          float* bI, float* bF, float* bG, float* bO){
  #pragma unroll
  for (int j=0;j<4;j++){
    int col = cb + q*4 + j;
    bI[j] = bi[col]        + bh[col];
    bF[j] = bi[512 + col]  + bh[512 + col];
    bG[j] = bi[1024 + col] + bh[1024 + col];
    bO[j] = bi[1536 + col] + bh[1536 + col];
  }
}

__global__ __launch_bounds__(NT) void lstm_persistent(Params p){
  __shared__ f16 wlds[32768];  // 64 KB
  const int tid = threadIdx.x;
  const int bid = blockIdx.x;
  const int lane = tid & 63;
  const int wave = tid >> 6;
  const int kg = lane >> 4;
  const int ln = lane & 15;
  const int q = kg & 1;
  const bool hi = lane >= 32;
  const bool isL1 = bid >= 64;
  const int layer = isL1 ? 1 : 0;
  const int cb = (isL1 ? bid - 64 : bid) * 8;   // h-column base
  const int KC = isL1 ? 32 : 22;                // k-chunks
  const int KX = isL1 ? 512 : KXPAD;            // boundary between x-part and h-part
  const int SI = isL1 ? 512 : DIN;              // Wih row stride

  u32* grp  = p.cnt;          // 16 group counters, 128B apart
  u32* root = p.cnt + 512;

  load_weights(p.W_i[0][layer], p.W_h[0][layer], KC, KX, SI, cb, wlds);
  float bI[4],bF[4],bG[4],bO[4];
  load_bias(p.b_i[0][layer], p.b_h[0][layer], cb, q, bI,bF,bG,bO);

  float c[4] = {0.f,0.f,0.f,0.f};
  half4 hsave = {(f16)0.f,(f16)0.f,(f16)0.f,(f16)0.f};
  const int b = wave*16 + ln;          // batch index this lane covers
  const int colb = cb + q*4;           // h-col base this lane writes
  bool bailed = false;

  for (int s=0; s<STOT; ++s){
    const int pr = (s-1)&1;   // read parity ((-1)&1 == 1)
    const int pw = s&1;       // write parity
    bool act=false, rew=false, sh=false; const f16* xsrc=nullptr; int t=0; int hsj=0;
    if (!isL1){
      if (s<=1024){ act=true; xsrc=p.xh; t=s; }
      else if (s==1025){ rew=true; }
      else if (s<=2048){ act=true; xsrc=p.dh; t=s-1026; }
    } else {
      if (s>=1 && s<=1025){ act=true; }
      else if (s==1026){ rew=true; }
      else if (s>=1027){ act=true; sh=true; hsj=s-1027; }
    }

    if (act){
      const f16* h0r = p.h0 + (size_t)pr*(NBAT*HD);
      float4v acc0 = {0.f,0.f,0.f,0.f};
      float4v acc1 = {0.f,0.f,0.f,0.f};
      const f16* wb0 = wlds + lane*8;
      const f16* wb1 = wlds + (size_t)KC*512 + lane*8;
      if (!isL1){
        const f16* xb = xsrc + ((size_t)t*NBAT + b)*KXPAD + kg*8;
        const f16* hb = h0r + (size_t)b*HD + kg*8;
        #pragma unroll
        for (int kc=0;kc<6;kc++){
          half8 bf = *(const half8*)(xb + kc*32);
          acc0 = mfma16(*(const half8*)(wb0 + kc*512), bf, acc0);
          acc1 = mfma16(*(const half8*)(wb1 + kc*512), bf, acc1);
        }
        #pragma unroll
        for (int kc=6;kc<22;kc++){
          half8 bf = *(const half8*)(hb + (kc-6)*32);
          acc0 = mfma16(*(const half8*)(wb0 + kc*512), bf, acc0);
          acc1 = mfma16(*(const half8*)(wb1 + kc*512), bf, acc1);
        }
      } else {
        const f16* hb0 = h0r + (size_t)b*HD + kg*8;
        const f16* hb1 = p.h1 + (size_t)pr*(NBAT*HD) + (size_t)b*HD + kg*8;
        #pragma unroll
        for (int kc=0;kc<16;kc++){
          half8 bf = *(const half8*)(hb0 + kc*32);
          acc0 = mfma16(*(const half8*)(wb0 + kc*512), bf, acc0);
          acc1 = mfma16(*(const half8*)(wb1 + kc*512), bf, acc1);
        }
        #pragma unroll
        for (int kc=16;kc<32;kc++){
          half8 bf = *(const half8*)(hb1 + (kc-16)*32);
          acc0 = mfma16(*(const half8*)(wb0 + kc*512), bf, acc0);
          acc1 = mfma16(*(const half8*)(wb1 + kc*512), bf, acc1);
        }
      }
      // epilogue: lanes<32 hold i/g rows, lanes>=32 hold f/o rows (same cols).
      half4 hv;
      #pragma unroll
      for (int j=0;j<4;j++){
        float s0 = __shfl_xor(acc0[j], 32);
        float s1 = __shfl_xor(acc1[j], 32);
        float iv = (hi ? s0 : acc0[j]) + bI[j];
        float fv = (hi ? acc0[j] : s0) + bF[j];
        float gv = (hi ? s1 : acc1[j]) + bG[j];
        float ov = (hi ? acc1[j] : s1) + bO[j];
        c[j] = sigf(fv)*c[j] + sigf(iv)*tanhf_(gv);
        float hval = sigf(ov)*tanhf_(c[j]);
        hv[j] = (f16)hval;
      }
      hsave = hv;
      if (!hi){
        f16* hw = (isL1 ? p.h1 : p.h0) + (size_t)pw*(NBAT*HD) + (size_t)b*HD + colb;
        *(half4*)hw = hv;
        if (sh) *(half4*)(p.hs + ((size_t)hsj*NBAT + b)*HD + colb) = hv;
      }
    } else if (rew){
      // re-publish final phase-state into current parity for the decoder
      if (!hi){
        f16* hw = (isL1 ? p.h1 : p.h0) + (size_t)pw*(NBAT*HD) + (size_t)b*HD + colb;
        *(half4*)hw = hsave;
      }
    }

    if (s==1025 && !isL1){
      load_weights(p.W_i[1][0], p.W_h[1][0], KC, KX, SI, cb, wlds);
      load_bias(p.b_i[1][0], p.b_h[1][0], cb, q, bI,bF,bG,bO);
    }
    if (s==1026 && isL1){
      load_weights(p.W_i[1][1], p.W_h[1][1], KC, KX, SI, cb, wlds);
      load_bias(p.b_i[1][1], p.b_h[1][1], cb, q, bI,bF,bG,bO);
    }

    // ---- one-phase monotonic grid barrier ----
    __threadfence();           // release: flush h writes to coherence point
    __syncthreads();
    if (tid==0){
      u32 g = (u32)(bid >> 3);
      u32 old = atomicAdd(&grp[g*32], 1u);
      if (old == (u32)(8*(s+1)-1)) atomicAdd(root, 1u);
      if (!bailed){
        u32 tgt = (u32)(16*(s+1));
        int guard = 0;
        while (__hip_atomic_load(root, __ATOMIC_RELAXED, __HIP_MEMORY_SCOPE_AGENT) < tgt){
          __builtin_amdgcn_s_sleep(2);
          if (++guard > (1<<17)){ bailed = true; break; }  // safety: no deadlock
        }
      }
    }
    __syncthreads();
    __threadfence();           // acquire: invalidate stale cached h lines
  }
}

// Build fp16 padded input streams, fp16 classifier weights, zero out[:,0,:].
__global__ void prepass(const float* x, const float* y, const float* W1, const float* W2,
                        f16* xh, f16* dh, f16* W1h, f16* W2h, float* out){
  const size_t NXH = (size_t)TENC*NBAT*KXPAD;
  const size_t NDH = (size_t)TDEC*NBAT*KXPAD;
  const size_t NW1 = 256*512;
  const size_t NW2 = 176*256;
  const size_t NZ  = (size_t)NBAT*DIN;
  const size_t TOTAL = NXH+NDH+NW1+NW2+NZ;
  for (size_t i = (size_t)blockIdx.x*blockDim.x + threadIdx.x; i < TOTAL;
       i += (size_t)gridDim.x*blockDim.x){
    if (i < NXH){
      size_t t = i/(NBAT*KXPAD); size_t r = i%(NBAT*KXPAD);
      size_t bb = r/KXPAD; size_t k = r%KXPAD;
      float v = (t>=1 && k<DIN) ? x[(bb*1024 + (t-1))*DIN + k] : 0.f;
      xh[i] = (f16)v;
    } else if (i < NXH+NDH){
      size_t j = i-NXH;
      size_t t = j/(NBAT*KXPAD); size_t r = j%(NBAT*KXPAD);
      size_t bb = r/KXPAD; size_t k = r%KXPAD;
      float v = (t>=1 && k<DIN) ? y[(bb*1024 + (t-1))*DIN + k] : 0.f;
      dh[j] = (f16)v;
    } else if (i < NXH+NDH+NW1){
      size_t j = i-NXH-NDH; W1h[j] = (f16)W1[j];
    } else if (i < NXH+NDH+NW1+NW2){
      size_t j = i-NXH-NDH-NW1; W2h[j] = (f16)W2[j];
    } else {
      size_t j = i-NXH-NDH-NW1-NW2;
      size_t bb = j/DIN; size_t k = j%DIN;
      out[bb*1024*DIN + k] = 0.f;
    }
  }
}

// Fused classifier: out[b][1+t][:] = relu(hs[t][b]·W1^T + b1)·W2^T + b2
__global__ __launch_bounds__(NT) void cls_kernel(const f16* hs, const f16* W1h, const f16* W2h,
                                                 const float* b1, const float* b2, float* out){
  __shared__ f16 hm[64*264];   // hmid tile, padded stride to dodge bank conflicts
  const int tid = threadIdx.x;
  const int lane = tid & 63, wave = tid >> 6;
  const int kg = lane >> 4, ln = lane & 15;
  const int m0 = blockIdx.x * 64;

  float4v acc[4][4];
  #pragma unroll
  for (int mt=0;mt<4;mt++)
    #pragma unroll
    for (int nt=0;nt<4;nt++) acc[mt][nt] = (float4v){0.f,0.f,0.f,0.f};

  #pragma unroll
  for (int kc=0;kc<16;kc++){
    half8 av[4];
    #pragma unroll
    for (int mt=0;mt<4;mt++)
      av[mt] = *(const half8*)(hs + (size_t)(m0 + mt*16 + ln)*HD + kc*32 + kg*8);
    #pragma unroll
    for (int nt=0;nt<4;nt++){
      half8 bf = *(const half8*)(W1h + (size_t)(wave*64 + nt*16 + ln)*HD + kc*32 + kg*8);
      #pragma unroll
      for (int mt=0;mt<4;mt++) acc[mt][nt] = mfma16(av[mt], bf, acc[mt][nt]);
    }
  }
  #pragma unroll
  for (int nt=0;nt<4;nt++){
    float bv = b1[wave*64 + nt*16 + ln];
    #pragma unroll
    for (int mt=0;mt<4;mt++)
      #pragma unroll
      for (int j=0;j<4;j++){
        float v = acc[mt][nt][j] + bv;
        v = v > 0.f ? v : 0.f;
        hm[(mt*16 + kg*4 + j)*264 + (wave*64 + nt*16 + ln)] = (f16)v;
      }
  }
  __syncthreads();
  for (int nt2 = wave; nt2 < 11; nt2 += 4){
    float4v a2[4];
    #pragma unroll
    for (int mt=0;mt<4;mt++) a2[mt] = (float4v){0.f,0.f,0.f,0.f};
    #pragma unroll
    for (int kc=0;kc<8;kc++){
      half8 bf = *(const half8*)(W2h + (size_t)(nt2*16 + ln)*256 + kc*32 + kg*8);
      #pragma unroll
      for (int mt=0;mt<4;mt++){
        half8 av = *(const half8*)(hm + (size_t)(mt*16 + ln)*264 + kc*32 + kg*8);
        a2[mt] = mfma16(av, bf, a2[mt]);
      }
    }
    float bv = b2[nt2*16 + ln];
    #pragma unroll
    for (int mt=0;mt<4;mt++)
      #pragma unroll
      for (int j=0;j<4;j++){
        int m = m0 + mt*16 + kg*4 + j;
        int bb = m & 63; int t = m >> 6;
        out[((size_t)bb*1024 + 1 + t)*DIN + nt2*16 + ln] = a2[mt][j] + bv;
      }
  }
}

extern "C" void kernel_launch(void* const* d_in, const int* in_sizes, int n_in,
                              void* d_out, int out_size, void* d_ws, size_t ws_size,
                              hipStream_t stream){
  if (ws_size < WS_END) return;  // need ~113 MB scratch
  const float* x = (const float*)d_in[0];
  const float* y = (const float*)d_in[1];

  char* ws = (char*)d_ws;
  u32* cnt = (u32*)(ws + WS_CNT);
  f16* h0  = (f16*)(ws + WS_H0);
  f16* h1  = (f16*)(ws + WS_H1);
  f16* xh  = (f16*)(ws + WS_XH);
  f16* dh  = (f16*)(ws + WS_DH);
  f16* hs  = (f16*)(ws + WS_HS);
  f16* W1h = (f16*)(ws + WS_W1);
  f16* W2h = (f16*)(ws + WS_W2);

  // zero counters + h state buffers
  hipMemsetAsync(ws, 0, WS_ZERO_END, stream);

  prepass<<<4096, NT, 0, stream>>>(x, y, (const float*)d_in[18], (const float*)d_in[20],
                                   xh, dh, W1h, W2h, (float*)d_out);

  Params p;
  p.W_i[0][0] = (const float*)d_in[2];  p.W_h[0][0] = (const float*)d_in[3];
  p.b_i[0][0] = (const float*)d_in[4];  p.b_h[0][0] = (const float*)d_in[5];
  p.W_i[0][1] = (const float*)d_in[6];  p.W_h[0][1] = (const float*)d_in[7];
  p.b_i[0][1] = (const float*)d_in[8];  p.b_h[0][1] = (const float*)d_in[9];
  p.W_i[1][0] = (const float*)d_in[10]; p.W_h[1][0] = (const float*)d_in[11];
  p.b_i[1][0] = (const float*)d_in[12]; p.b_h[1][0] = (const float*)d_in[13];
  p.W_i[1][1] = (const float*)d_in[14]; p.W_h[1][1] = (const float*)d_in[15];
  p.b_i[1][1] = (const float*)d_in[16]; p.b_h[1][1] = (const float*)d_in[17];
  p.xh = xh; p.dh = dh; p.h0 = h0; p.h1 = h1; p.hs = hs; p.cnt = cnt;

  lstm_persistent<<<NB, NT, 0, stream>>>(p);

  cls_kernel<<<TDEC, NT, 0, stream>>>(hs, W1h, W2h,
                                      (const float*)d_in[19], (const float*)d_in[21],
                                      (float*)d_out);
}

// Round 6
// 23732.573 us; speedup vs baseline: 2.4277x; 2.4277x over previous
//
#include <hip/hip_runtime.h>

typedef _Float16 f16;
typedef _Float16 half8 __attribute__((ext_vector_type(8)));
typedef _Float16 half4 __attribute__((ext_vector_type(4)));
typedef float float4v __attribute__((ext_vector_type(4)));
typedef unsigned int u32;
typedef unsigned long long u64;

constexpr int NB = 128;      // persistent blocks (64 L0 + 64 L1)
constexpr int NT = 256;      // threads per block (4 waves)
constexpr int HD = 512;      // hidden size
constexpr int NBAT = 64;     // batch
constexpr int DIN = 176;     // input feature dim
constexpr int KXPAD = 192;   // padded input dim (176 -> 192, multiple of 32)
constexpr int TENC = 1025;   // encoder steps
constexpr int TDEC = 1023;   // decoder steps
constexpr int STOT = 2050;   // total global steps (enc 1026 + dec 1024)

// ---- ws layout (bytes) ----
constexpr size_t WS_CNT = 0;          // counters (4 KB)
constexpr size_t WS_H0  = 4096;       // h0 [2][64][512] f16  (128 KB)
constexpr size_t WS_H1  = 135168;     // h1 [2][64][512] f16  (128 KB)
constexpr size_t WS_ZERO_END = 266240;
constexpr size_t WS_XH  = 266240;     // xh [1025][64][192] f16
constexpr size_t WS_DH  = 25456640;   // dh [1023][64][192] f16
constexpr size_t WS_HS  = 50597888;   // hs [1023][64][512] f16
constexpr size_t WS_W1  = 117641216;  // W1h [256][512] f16
constexpr size_t WS_W2  = 117903360;  // W2h [176][256] f16
constexpr size_t WS_END = 117993472;

__device__ __forceinline__ float sigf(float x){ return 1.f/(1.f + __expf(-x)); }
__device__ __forceinline__ float tanhf_(float x){ return 2.f/(1.f + __expf(-2.f*x)) - 1.f; }

__device__ __forceinline__ float4v mfma16(half8 a, half8 b, float4v c){
  return __builtin_amdgcn_mfma_f32_16x16x32_f16(a, b, c, 0, 0, 0);
}

// SYSTEM scope => sc0 sc1 on gfx950: loads bypass L1+L2 (read MALL), stores
// write through L1+L2 to MALL. Relaxed => no cache-maintenance instructions.
__device__ __forceinline__ u64 coh_ld(const u64* p){
  return __hip_atomic_load(p, __ATOMIC_RELAXED, __HIP_MEMORY_SCOPE_SYSTEM);
}
__device__ __forceinline__ void coh_st(u64* p, u64 v){
  __hip_atomic_store(p, v, __ATOMIC_RELAXED, __HIP_MEMORY_SCOPE_SYSTEM);
}

union U16 { u64 u[2]; half8 h; };
union U8  { u64 u; half4 h; };

struct Params {
  const float* W_i[2][2];  // [phase][layer] input-weight (4H x din)
  const float* W_h[2][2];  // recurrent weight (4H x 512)
  const float* b_i[2][2];
  const float* b_h[2][2];
  f16* xh; f16* dh; f16* h0; f16* h1; f16* hs;
  u32* cnt;
};

// Load this block's weight slice into LDS in MFMA-fragment-major layout.
// Slot idx = (mt*KC + kc)*64 + lane ; each slot = 8 f16 (row = lane&15 within
// M-tile, k = kc*32 + (lane>>4)*8 + j).  M-tile0 rows = [i(cb..cb+7), f(..)],
// M-tile1 = [g, o].
__device__ void load_weights(const float* Wi, const float* Wh, int KC, int KX,
                             int SI, int cb, f16* wlds){
  __syncthreads();
  const int slots = 2*KC*64;
  for (int idx = threadIdx.x; idx < slots; idx += NT){
    int mt = idx / (KC*64);
    int rem = idx - mt*(KC*64);
    int kc = rem >> 6;
    int l = rem & 63;
    int r = l & 15;
    int kgg = l >> 4;
    int grow;
    if (mt==0) grow = (r<8) ? (cb + r) : (512 + cb + (r-8));
    else       grow = (r<8) ? (1024 + cb + r) : (1536 + cb + (r-8));
    int k0 = kc*32 + kgg*8;
    f16* dst = wlds + (size_t)idx*8;
    #pragma unroll
    for (int j=0;j<8;j++){
      int k = k0 + j;
      float v;
      if (k < KX) v = (k < SI) ? Wi[(size_t)grow*SI + k] : 0.f;
      else        v = Wh[(size_t)grow*HD + (k - KX)];
      dst[j] = (f16)v;
    }
  }
  __syncthreads();
}

__device__ void load_bias(const float* bi, const float* bh, int cb, int q,
                          float* bI, float* bF, float* bG, float* bO){
  #pragma unroll
  for (int j=0;j<4;j++){
    int col = cb + q*4 + j;
    bI[j] = bi[col]        + bh[col];
    bF[j] = bi[512 + col]  + bh[512 + col];
    bG[j] = bi[1024 + col] + bh[1024 + col];
    bO[j] = bi[1536 + col] + bh[1536 + col];
  }
}

__global__ __launch_bounds__(NT, 1) void lstm_persistent(Params p){
  __shared__ f16 wlds[32768];  // 64 KB
  const int tid = threadIdx.x;
  const int bid = blockIdx.x;
  const int lane = tid & 63;
  const int wave = tid >> 6;
  const int kg = lane >> 4;
  const int ln = lane & 15;
  const int q = kg & 1;
  const bool hi = lane >= 32;
  const bool isL1 = bid >= 64;
  const int layer = isL1 ? 1 : 0;
  const int cb = (isL1 ? bid - 64 : bid) * 8;   // h-column base
  const int KC = isL1 ? 32 : 22;                // k-chunks
  const int KX = isL1 ? 512 : KXPAD;            // boundary between x-part and h-part
  const int SI = isL1 ? 512 : DIN;              // Wih row stride

  u32* grp  = p.cnt;          // 16 group counters, 128B apart
  u32* root = p.cnt + 512;

  load_weights(p.W_i[0][layer], p.W_h[0][layer], KC, KX, SI, cb, wlds);
  float bI[4],bF[4],bG[4],bO[4];
  load_bias(p.b_i[0][layer], p.b_h[0][layer], cb, q, bI,bF,bG,bO);

  float c[4] = {0.f,0.f,0.f,0.f};
  half4 hsave = {(f16)0.f,(f16)0.f,(f16)0.f,(f16)0.f};
  const int b = wave*16 + ln;          // batch index this lane covers
  const int colb = cb + q*4;           // h-col base this lane writes
  bool bailed = false;

  // x-fragment prefetch registers (L0 only)
  half8 xpre[6];
  if (!isL1){
    const f16* xb = p.xh + ((size_t)0*NBAT + b)*KXPAD + kg*8;
    #pragma unroll
    for (int kc=0;kc<6;kc++) xpre[kc] = *(const half8*)(xb + kc*32);
  }

  for (int s=0; s<STOT; ++s){
    const int pr = (s-1)&1;   // read parity ((-1)&1 == 1)
    const int pw = s&1;       // write parity
    bool act=false, rew=false, sh=false; int hsj=0;
    if (!isL1){
      if (s<=1024){ act=true; }
      else if (s==1025){ rew=true; }
      else if (s<=2048){ act=true; }
    } else {
      if (s>=1 && s<=1025){ act=true; }
      else if (s==1026){ rew=true; }
      else if (s>=1027){ act=true; sh=true; hsj=s-1027; }
    }

    if (act){
      float4v acc0 = {0.f,0.f,0.f,0.f};
      float4v acc1 = {0.f,0.f,0.f,0.f};
      const f16* wb0 = wlds + lane*8;
      const f16* wb1 = wlds + (size_t)KC*512 + lane*8;
      if (!isL1){
        // 16 h-chunks: chunk c2 = 32 halves = 64 bytes = 8 u64 stride
        u64 hu[32];
        const u64* hp = (const u64*)(p.h0 + (size_t)pr*(NBAT*HD) + (size_t)b*HD + kg*8);
        #pragma unroll
        for (int c2=0;c2<16;c2++){
          hu[2*c2]   = coh_ld(hp + c2*8);
          hu[2*c2+1] = coh_ld(hp + c2*8 + 1);
        }
        // x-part MFMAs from prefetched registers (overlap h-load latency)
        #pragma unroll
        for (int kc=0;kc<6;kc++){
          acc0 = mfma16(*(const half8*)(wb0 + kc*512), xpre[kc], acc0);
          acc1 = mfma16(*(const half8*)(wb1 + kc*512), xpre[kc], acc1);
        }
        // h-part MFMAs
        #pragma unroll
        for (int c2=0;c2<16;c2++){
          U16 v; v.u[0]=hu[2*c2]; v.u[1]=hu[2*c2+1];
          acc0 = mfma16(*(const half8*)(wb0 + (6+c2)*512), v.h, acc0);
          acc1 = mfma16(*(const half8*)(wb1 + (6+c2)*512), v.h, acc1);
        }
      } else {
        u64 hu0[32], hu1[32];
        const u64* hp0 = (const u64*)(p.h0 + (size_t)pr*(NBAT*HD) + (size_t)b*HD + kg*8);
        const u64* hp1 = (const u64*)(p.h1 + (size_t)pr*(NBAT*HD) + (size_t)b*HD + kg*8);
        #pragma unroll
        for (int c2=0;c2<16;c2++){
          hu0[2*c2]   = coh_ld(hp0 + c2*8);
          hu0[2*c2+1] = coh_ld(hp0 + c2*8 + 1);
        }
        #pragma unroll
        for (int c2=0;c2<16;c2++){
          hu1[2*c2]   = coh_ld(hp1 + c2*8);
          hu1[2*c2+1] = coh_ld(hp1 + c2*8 + 1);
        }
        #pragma unroll
        for (int c2=0;c2<16;c2++){
          U16 v; v.u[0]=hu0[2*c2]; v.u[1]=hu0[2*c2+1];
          acc0 = mfma16(*(const half8*)(wb0 + c2*512), v.h, acc0);
          acc1 = mfma16(*(const half8*)(wb1 + c2*512), v.h, acc1);
        }
        #pragma unroll
        for (int c2=0;c2<16;c2++){
          U16 v; v.u[0]=hu1[2*c2]; v.u[1]=hu1[2*c2+1];
          acc0 = mfma16(*(const half8*)(wb0 + (16+c2)*512), v.h, acc0);
          acc1 = mfma16(*(const half8*)(wb1 + (16+c2)*512), v.h, acc1);
        }
      }
      // epilogue: lanes<32 hold i/g rows, lanes>=32 hold f/o rows (same cols).
      half4 hv;
      #pragma unroll
      for (int j=0;j<4;j++){
        float s0 = __shfl_xor(acc0[j], 32);
        float s1 = __shfl_xor(acc1[j], 32);
        float iv = (hi ? s0 : acc0[j]) + bI[j];
        float fv = (hi ? acc0[j] : s0) + bF[j];
        float gv = (hi ? s1 : acc1[j]) + bG[j];
        float ov = (hi ? acc1[j] : s1) + bO[j];
        c[j] = sigf(fv)*c[j] + sigf(iv)*tanhf_(gv);
        float hval = sigf(ov)*tanhf_(c[j]);
        hv[j] = (f16)hval;
      }
      hsave = hv;
      if (!hi){
        f16* hw = (isL1 ? p.h1 : p.h0) + (size_t)pw*(NBAT*HD) + (size_t)b*HD + colb;
        U8 uu; uu.h = hv;
        coh_st((u64*)hw, uu.u);                      // write-through to MALL
        if (sh) *(half4*)(p.hs + ((size_t)hsj*NBAT + b)*HD + colb) = hv;  // cached
      }
    } else if (rew){
      // re-publish final phase-state into current parity for the decoder
      if (!hi){
        f16* hw = (isL1 ? p.h1 : p.h0) + (size_t)pw*(NBAT*HD) + (size_t)b*HD + colb;
        U8 uu; uu.h = hsave;
        coh_st((u64*)hw, uu.u);
      }
    }

    // prefetch next step's x-fragments (L0 only; cached loads, read-only data)
    if (!isL1){
      int s2 = s+1; const f16* xs2=nullptr; int t2=0;
      if (s2<=1024){ xs2=p.xh; t2=s2; }
      else if (s2>=1026 && s2<=2048){ xs2=p.dh; t2=s2-1026; }
      if (xs2){
        const f16* xb = xs2 + ((size_t)t2*NBAT + b)*KXPAD + kg*8;
        #pragma unroll
        for (int kc=0;kc<6;kc++) xpre[kc] = *(const half8*)(xb + kc*32);
      }
    }

    if (s==1025 && !isL1){
      load_weights(p.W_i[1][0], p.W_h[1][0], KC, KX, SI, cb, wlds);
      load_bias(p.b_i[1][0], p.b_h[1][0], cb, q, bI,bF,bG,bO);
    }
    if (s==1026 && isL1){
      load_weights(p.W_i[1][1], p.W_h[1][1], KC, KX, SI, cb, wlds);
      load_bias(p.b_i[1][1], p.b_h[1][1], cb, q, bI,bF,bG,bO);
    }

    // ---- one-phase monotonic grid barrier ----
    // __syncthreads drains vmcnt -> all write-through h-stores are at the MALL
    // before tid0 signals arrival (release); readers use sc0sc1 loads that read
    // the MALL directly (acquire), so no buffer_wbl2/buffer_inv is needed.
    __syncthreads();
    if (tid==0){
      u32 g = (u32)(bid >> 3);
      u32 old = atomicAdd(&grp[g*32], 1u);
      if (old == (u32)(8*(s+1)-1)) atomicAdd(root, 1u);
      if (!bailed){
        u32 tgt = (u32)(16*(s+1));
        int guard = 0;
        while (__hip_atomic_load(root, __ATOMIC_RELAXED, __HIP_MEMORY_SCOPE_SYSTEM) < tgt){
          __builtin_amdgcn_s_sleep(2);
          if (++guard > (1<<17)){ bailed = true; break; }  // safety: no deadlock
        }
      }
    }
    __syncthreads();
  }
}

// Build fp16 padded input streams, fp16 classifier weights, zero out[:,0,:].
__global__ void prepass(const float* x, const float* y, const float* W1, const float* W2,
                        f16* xh, f16* dh, f16* W1h, f16* W2h, float* out){
  const size_t NXH = (size_t)TENC*NBAT*KXPAD;
  const size_t NDH = (size_t)TDEC*NBAT*KXPAD;
  const size_t NW1 = 256*512;
  const size_t NW2 = 176*256;
  const size_t NZ  = (size_t)NBAT*DIN;
  const size_t TOTAL = NXH+NDH+NW1+NW2+NZ;
  for (size_t i = (size_t)blockIdx.x*blockDim.x + threadIdx.x; i < TOTAL;
       i += (size_t)gridDim.x*blockDim.x){
    if (i < NXH){
      size_t t = i/(NBAT*KXPAD); size_t r = i%(NBAT*KXPAD);
      size_t bb = r/KXPAD; size_t k = r%KXPAD;
      float v = (t>=1 && k<DIN) ? x[(bb*1024 + (t-1))*DIN + k] : 0.f;
      xh[i] = (f16)v;
    } else if (i < NXH+NDH){
      size_t j = i-NXH;
      size_t t = j/(NBAT*KXPAD); size_t r = j%(NBAT*KXPAD);
      size_t bb = r/KXPAD; size_t k = r%KXPAD;
      float v = (t>=1 && k<DIN) ? y[(bb*1024 + (t-1))*DIN + k] : 0.f;
      dh[j] = (f16)v;
    } else if (i < NXH+NDH+NW1){
      size_t j = i-NXH-NDH; W1h[j] = (f16)W1[j];
    } else if (i < NXH+NDH+NW1+NW2){
      size_t j = i-NXH-NDH-NW1; W2h[j] = (f16)W2[j];
    } else {
      size_t j = i-NXH-NDH-NW1-NW2;
      size_t bb = j/DIN; size_t k = j%DIN;
      out[bb*1024*DIN + k] = 0.f;
    }
  }
}

// Fused classifier: out[b][1+t][:] = relu(hs[t][b]·W1^T + b1)·W2^T + b2
__global__ __launch_bounds__(NT) void cls_kernel(const f16* hs, const f16* W1h, const f16* W2h,
                                                 const float* b1, const float* b2, float* out){
  __shared__ f16 hm[64*264];   // hmid tile, padded stride to dodge bank conflicts
  const int tid = threadIdx.x;
  const int lane = tid & 63, wave = tid >> 6;
  const int kg = lane >> 4, ln = lane & 15;
  const int m0 = blockIdx.x * 64;

  float4v acc[4][4];
  #pragma unroll
  for (int mt=0;mt<4;mt++)
    #pragma unroll
    for (int nt=0;nt<4;nt++) acc[mt][nt] = (float4v){0.f,0.f,0.f,0.f};

  #pragma unroll
  for (int kc=0;kc<16;kc++){
    half8 av[4];
    #pragma unroll
    for (int mt=0;mt<4;mt++)
      av[mt] = *(const half8*)(hs + (size_t)(m0 + mt*16 + ln)*HD + kc*32 + kg*8);
    #pragma unroll
    for (int nt=0;nt<4;nt++){
      half8 bf = *(const half8*)(W1h + (size_t)(wave*64 + nt*16 + ln)*HD + kc*32 + kg*8);
      #pragma unroll
      for (int mt=0;mt<4;mt++) acc[mt][nt] = mfma16(av[mt], bf, acc[mt][nt]);
    }
  }
  #pragma unroll
  for (int nt=0;nt<4;nt++){
    float bv = b1[wave*64 + nt*16 + ln];
    #pragma unroll
    for (int mt=0;mt<4;mt++)
      #pragma unroll
      for (int j=0;j<4;j++){
        float v = acc[mt][nt][j] + bv;
        v = v > 0.f ? v : 0.f;
        hm[(mt*16 + kg*4 + j)*264 + (wave*64 + nt*16 + ln)] = (f16)v;
      }
  }
  __syncthreads();
  for (int nt2 = wave; nt2 < 11; nt2 += 4){
    float4v a2[4];
    #pragma unroll
    for (int mt=0;mt<4;mt++) a2[mt] = (float4v){0.f,0.f,0.f,0.f};
    #pragma unroll
    for (int kc=0;kc<8;kc++){
      half8 bf = *(const half8*)(W2h + (size_t)(nt2*16 + ln)*256 + kc*32 + kg*8);
      #pragma unroll
      for (int mt=0;mt<4;mt++){
        half8 av = *(const half8*)(hm + (size_t)(mt*16 + ln)*264 + kc*32 + kg*8);
        a2[mt] = mfma16(av, bf, a2[mt]);
      }
    }
    float bv = b2[nt2*16 + ln];
    #pragma unroll
    for (int mt=0;mt<4;mt++)
      #pragma unroll
      for (int j=0;j<4;j++){
        int m = m0 + mt*16 + kg*4 + j;
        int bb = m & 63; int t = m >> 6;
        out[((size_t)bb*1024 + 1 + t)*DIN + nt2*16 + ln] = a2[mt][j] + bv;
      }
  }
}

extern "C" void kernel_launch(void* const* d_in, const int* in_sizes, int n_in,
                              void* d_out, int out_size, void* d_ws, size_t ws_size,
                              hipStream_t stream){
  if (ws_size < WS_END) return;  // need ~113 MB scratch
  const float* x = (const float*)d_in[0];
  const float* y = (const float*)d_in[1];

  char* ws = (char*)d_ws;
  u32* cnt = (u32*)(ws + WS_CNT);
  f16* h0  = (f16*)(ws + WS_H0);
  f16* h1  = (f16*)(ws + WS_H1);
  f16* xh  = (f16*)(ws + WS_XH);
  f16* dh  = (f16*)(ws + WS_DH);
  f16* hs  = (f16*)(ws + WS_HS);
  f16* W1h = (f16*)(ws + WS_W1);
  f16* W2h = (f16*)(ws + WS_W2);

  // zero counters + h state buffers
  hipMemsetAsync(ws, 0, WS_ZERO_END, stream);

  prepass<<<4096, NT, 0, stream>>>(x, y, (const float*)d_in[18], (const float*)d_in[20],
                                   xh, dh, W1h, W2h, (float*)d_out);

  Params p;
  p.W_i[0][0] = (const float*)d_in[2];  p.W_h[0][0] = (const float*)d_in[3];
  p.b_i[0][0] = (const float*)d_in[4];  p.b_h[0][0] = (const float*)d_in[5];
  p.W_i[0][1] = (const float*)d_in[6];  p.W_h[0][1] = (const float*)d_in[7];
  p.b_i[0][1] = (const float*)d_in[8];  p.b_h[0][1] = (const float*)d_in[9];
  p.W_i[1][0] = (const float*)d_in[10]; p.W_h[1][0] = (const float*)d_in[11];
  p.b_i[1][0] = (const float*)d_in[12]; p.b_h[1][0] = (const float*)d_in[13];
  p.W_i[1][1] = (const float*)d_in[14]; p.W_h[1][1] = (const float*)d_in[15];
  p.b_i[1][1] = (const float*)d_in[16]; p.b_h[1][1] = (const float*)d_in[17];
  p.xh = xh; p.dh = dh; p.h0 = h0; p.h1 = h1; p.hs = hs; p.cnt = cnt;

  lstm_persistent<<<NB, NT, 0, stream>>>(p);

  cls_kernel<<<TDEC, NT, 0, stream>>>(hs, W1h, W2h,
                                      (const float*)d_in[19], (const float*)d_in[21],
                                      (float*)d_out);
}

// Round 7
// 14160.800 us; speedup vs baseline: 4.0687x; 1.6759x over previous
//
#include <hip/hip_runtime.h>

typedef _Float16 f16;
typedef _Float16 half8 __attribute__((ext_vector_type(8)));
typedef _Float16 half4 __attribute__((ext_vector_type(4)));
typedef float float4v __attribute__((ext_vector_type(4)));
typedef int int4v __attribute__((ext_vector_type(4)));
typedef unsigned int u32;
typedef unsigned long long u64;

constexpr int NB = 128;      // persistent blocks (64 L0 + 64 L1)
constexpr int NT = 256;      // threads per block (4 waves)
constexpr int HD = 512;      // hidden size
constexpr int NBAT = 64;     // batch
constexpr int DIN = 176;     // input feature dim
constexpr int KXPAD = 192;   // padded input dim (176 -> 192, multiple of 32)
constexpr int TENC = 1025;   // encoder steps
constexpr int TDEC = 1023;   // decoder steps
constexpr int STOT = 2050;   // total global steps (enc 1026 + dec 1024)

// ---- ws layout (bytes) ----
constexpr size_t WS_CNT = 0;          // 128 flags, 32B stride (4 KB)
constexpr size_t WS_H0  = 4096;       // h0 [2][64][512] f16  (128 KB)
constexpr size_t WS_H1  = 135168;     // h1 [2][64][512] f16  (128 KB)
constexpr size_t WS_ZERO_END = 266240;
constexpr size_t WS_XH  = 266240;     // xh [1025][64][192] f16
constexpr size_t WS_DH  = 25456640;   // dh [1023][64][192] f16
constexpr size_t WS_HS  = 50597888;   // hs [1023][64][512] f16
constexpr size_t WS_W1  = 117641216;  // W1h [256][512] f16
constexpr size_t WS_W2  = 117903360;  // W2h [176][256] f16
constexpr size_t WS_END = 117993472;

__device__ __forceinline__ float sigf(float x){ return 1.f/(1.f + __expf(-x)); }
__device__ __forceinline__ float tanhf_(float x){ return 2.f/(1.f + __expf(-2.f*x)) - 1.f; }

__device__ __forceinline__ float4v mfma16(half8 a, half8 b, float4v c){
  return __builtin_amdgcn_mfma_f32_16x16x32_f16(a, b, c, 0, 0, 0);
}

// 16B coherent load: sc0 sc1 -> bypass L1+L2, read the MALL (device coherence
// point). Plain load (not atomic) => fully pipelined; we do our own waitcnt.
__device__ __forceinline__ int4v ld16_coh(const void* p){
  int4v r;
  asm volatile("global_load_dwordx4 %0, %1, off sc0 sc1"
               : "=v"(r) : "v"(p) : "memory");
  return r;
}
// 8B coherent store: write-through L1+L2 to MALL.
__device__ __forceinline__ void st8_coh(void* p, u64 v){
  asm volatile("global_store_dwordx2 %0, %1, off sc0 sc1"
               :: "v"(p), "v"(v) : "memory");
}
// wait all vmem done; sched_barrier stops MFMAs hoisting above (rule #18).
__device__ __forceinline__ void wait_vm(){
  asm volatile("s_waitcnt vmcnt(0)" ::: "memory");
  __builtin_amdgcn_sched_barrier(0);
}
__device__ __forceinline__ void wait_vm16(){
  asm volatile("s_waitcnt vmcnt(16)" ::: "memory");
  __builtin_amdgcn_sched_barrier(0);
}

union U16a { int4v i; half8 h; };
union U8  { u64 u; half4 h; };

struct Params {
  const float* W_i[2][2];  // [phase][layer] input-weight (4H x din)
  const float* W_h[2][2];  // recurrent weight (4H x 512)
  const float* b_i[2][2];
  const float* b_h[2][2];
  f16* xh; f16* dh; f16* h0; f16* h1; f16* hs;
  u32* cnt;
};

// Load this block's weight slice into LDS in MFMA-fragment-major layout.
__device__ void load_weights(const float* Wi, const float* Wh, int KC, int KX,
                             int SI, int cb, f16* wlds){
  __syncthreads();
  const int slots = 2*KC*64;
  for (int idx = threadIdx.x; idx < slots; idx += NT){
    int mt = idx / (KC*64);
    int rem = idx - mt*(KC*64);
    int kc = rem >> 6;
    int l = rem & 63;
    int r = l & 15;
    int kgg = l >> 4;
    int grow;
    if (mt==0) grow = (r<8) ? (cb + r) : (512 + cb + (r-8));
    else       grow = (r<8) ? (1024 + cb + r) : (1536 + cb + (r-8));
    int k0 = kc*32 + kgg*8;
    f16* dst = wlds + (size_t)idx*8;
    #pragma unroll
    for (int j=0;j<8;j++){
      int k = k0 + j;
      float v;
      if (k < KX) v = (k < SI) ? Wi[(size_t)grow*SI + k] : 0.f;
      else        v = Wh[(size_t)grow*HD + (k - KX)];
      dst[j] = (f16)v;
    }
  }
  __syncthreads();
}

__device__ void load_bias(const float* bi, const float* bh, int cb, int q,
                          float* bI, float* bF, float* bG, float* bO){
  #pragma unroll
  for (int j=0;j<4;j++){
    int col = cb + q*4 + j;
    bI[j] = bi[col]        + bh[col];
    bF[j] = bi[512 + col]  + bh[512 + col];
    bG[j] = bi[1024 + col] + bh[1024 + col];
    bO[j] = bi[1536 + col] + bh[1536 + col];
  }
}

__global__ __launch_bounds__(NT, 1) void lstm_persistent(Params p){
  __shared__ f16 wlds[32768];  // 64 KB
  const int tid = threadIdx.x;
  const int bid = blockIdx.x;
  const int lane = tid & 63;
  const int wave = tid >> 6;
  const int kg = lane >> 4;
  const int ln = lane & 15;
  const int q = kg & 1;
  const bool hi = lane >= 32;
  const bool isL1 = bid >= 64;
  const int layer = isL1 ? 1 : 0;
  const int cb = (isL1 ? bid - 64 : bid) * 8;   // h-column base
  const int KC = isL1 ? 32 : 22;                // k-chunks
  const int KX = isL1 ? 512 : KXPAD;            // x/h boundary
  const int SI = isL1 ? 512 : DIN;              // Wih row stride

  u32* flags = p.cnt;         // 128 flags, 32B stride (flag i at cnt[i*8])

  load_weights(p.W_i[0][layer], p.W_h[0][layer], KC, KX, SI, cb, wlds);
  float bI[4],bF[4],bG[4],bO[4];
  load_bias(p.b_i[0][layer], p.b_h[0][layer], cb, q, bI,bF,bG,bO);

  float c[4] = {0.f,0.f,0.f,0.f};
  half4 hsave = {(f16)0.f,(f16)0.f,(f16)0.f,(f16)0.f};
  const int b = wave*16 + ln;          // batch index this lane covers
  const int colb = cb + q*4;           // h-col base this lane writes
  bool bailed = false;

  // x-fragment prefetch registers (L0 only)
  half8 xpre[6];
  if (!isL1){
    const f16* xb = p.xh + (size_t)b*KXPAD + kg*8;
    #pragma unroll
    for (int kc=0;kc<6;kc++) xpre[kc] = *(const half8*)(xb + kc*32);
  }

  for (int s=0; s<STOT; ++s){
    const int pr = (s-1)&1;   // read parity ((-1)&1 == 1)
    const int pw = s&1;       // write parity
    bool act=false, rew=false, sh=false; int hsj=0;
    if (!isL1){
      if (s<=1024){ act=true; }
      else if (s==1025){ rew=true; }
      else if (s<=2048){ act=true; }
    } else {
      if (s>=1 && s<=1025){ act=true; }
      else if (s==1026){ rew=true; }
      else if (s>=1027){ act=true; sh=true; hsj=s-1027; }
    }

    if (act){
      float4v acc0 = {0.f,0.f,0.f,0.f};
      float4v acc1 = {0.f,0.f,0.f,0.f};
      const f16* wb0 = wlds + lane*8;
      const f16* wb1 = wlds + (size_t)KC*512 + lane*8;
      if (!isL1){
        // burst-issue 16 coherent 16B h-loads (chunk c2 = 64B row stride)
        const char* hpc = (const char*)(p.h0 + (size_t)pr*(NBAT*HD) + (size_t)b*HD + kg*8);
        int4v hl[16];
        #pragma unroll
        for (int c2=0;c2<16;c2++) hl[c2] = ld16_coh(hpc + c2*64);
        // x-part MFMAs from prefetched registers (xpre completed before the
        // barrier's vmcnt drain -> no compiler wait here; overlaps h-loads)
        #pragma unroll
        for (int kc=0;kc<6;kc++){
          acc0 = mfma16(*(const half8*)(wb0 + kc*512), xpre[kc], acc0);
          acc1 = mfma16(*(const half8*)(wb1 + kc*512), xpre[kc], acc1);
        }
        wait_vm();
        #pragma unroll
        for (int c2=0;c2<16;c2++){
          U16a v; v.i = hl[c2];
          acc0 = mfma16(*(const half8*)(wb0 + (6+c2)*512), v.h, acc0);
          acc1 = mfma16(*(const half8*)(wb1 + (6+c2)*512), v.h, acc1);
        }
      } else {
        const char* hp0c = (const char*)(p.h0 + (size_t)pr*(NBAT*HD) + (size_t)b*HD + kg*8);
        const char* hp1c = (const char*)(p.h1 + (size_t)pr*(NBAT*HD) + (size_t)b*HD + kg*8);
        int4v hl0[16], hl1[16];
        #pragma unroll
        for (int c2=0;c2<16;c2++) hl0[c2] = ld16_coh(hp0c + c2*64);
        #pragma unroll
        for (int c2=0;c2<16;c2++) hl1[c2] = ld16_coh(hp1c + c2*64);
        wait_vm16();   // oldest 16 (h0) complete; h1 still in flight
        #pragma unroll
        for (int c2=0;c2<16;c2++){
          U16a v; v.i = hl0[c2];
          acc0 = mfma16(*(const half8*)(wb0 + c2*512), v.h, acc0);
          acc1 = mfma16(*(const half8*)(wb1 + c2*512), v.h, acc1);
        }
        wait_vm();
        #pragma unroll
        for (int c2=0;c2<16;c2++){
          U16a v; v.i = hl1[c2];
          acc0 = mfma16(*(const half8*)(wb0 + (16+c2)*512), v.h, acc0);
          acc1 = mfma16(*(const half8*)(wb1 + (16+c2)*512), v.h, acc1);
        }
      }
      // epilogue: lanes<32 hold i/g rows, lanes>=32 hold f/o rows (same cols).
      half4 hv;
      #pragma unroll
      for (int j=0;j<4;j++){
        float s0 = __shfl_xor(acc0[j], 32);
        float s1 = __shfl_xor(acc1[j], 32);
        float iv = (hi ? s0 : acc0[j]) + bI[j];
        float fv = (hi ? acc0[j] : s0) + bF[j];
        float gv = (hi ? s1 : acc1[j]) + bG[j];
        float ov = (hi ? acc1[j] : s1) + bO[j];
        c[j] = sigf(fv)*c[j] + sigf(iv)*tanhf_(gv);
        float hval = sigf(ov)*tanhf_(c[j]);
        hv[j] = (f16)hval;
      }
      hsave = hv;
      if (!hi){
        f16* hw = (isL1 ? p.h1 : p.h0) + (size_t)pw*(NBAT*HD) + (size_t)b*HD + colb;
        U8 uu; uu.h = hv;
        st8_coh(hw, uu.u);                           // write-through to MALL
        if (sh) *(half4*)(p.hs + ((size_t)hsj*NBAT + b)*HD + colb) = hv;  // cached
      }
    } else if (rew){
      if (!hi){
        f16* hw = (isL1 ? p.h1 : p.h0) + (size_t)pw*(NBAT*HD) + (size_t)b*HD + colb;
        U8 uu; uu.h = hsave;
        st8_coh(hw, uu.u);
      }
    }

    if (s==1025 && !isL1){
      load_weights(p.W_i[1][0], p.W_h[1][0], KC, KX, SI, cb, wlds);
      load_bias(p.b_i[1][0], p.b_h[1][0], cb, q, bI,bF,bG,bO);
    }
    if (s==1026 && isL1){
      load_weights(p.W_i[1][1], p.W_h[1][1], KC, KX, SI, cb, wlds);
      load_bias(p.b_i[1][1], p.b_h[1][1], cb, q, bI,bF,bG,bO);
    }

    // ---- flag-based grid barrier (single store per block, no RMW chain) ----
    __syncthreads();   // drains vmcnt per wave -> h-stores are at the MALL
    if (tid==0){
      __hip_atomic_store(flags + (size_t)bid*8, (u32)(s+1),
                         __ATOMIC_RELAXED, __HIP_MEMORY_SCOPE_SYSTEM);
    }
    // x-prefetch for next step in the poll window (off the arrival path)
    if (!isL1){
      int s2 = s+1; const f16* xs2=nullptr; int t2=0;
      if (s2<=1024){ xs2=p.xh; t2=s2; }
      else if (s2>=1026 && s2<=2048){ xs2=p.dh; t2=s2-1026; }
      if (xs2){
        const f16* xb = xs2 + ((size_t)t2*NBAT + b)*KXPAD + kg*8;
        #pragma unroll
        for (int kc=0;kc<6;kc++) xpre[kc] = *(const half8*)(xb + kc*32);
      }
    }
    // wave 0 polls all 128 flags in parallel (2 per lane)
    if (tid < 64){
      const u32 tgt = (u32)(s+1);
      const u32* f0 = flags + (size_t)lane*8;
      const u32* f1 = flags + (size_t)(lane+64)*8;
      int guard = 0;
      while (!bailed){
        u32 a = __hip_atomic_load(f0, __ATOMIC_RELAXED, __HIP_MEMORY_SCOPE_SYSTEM);
        u32 d = __hip_atomic_load(f1, __ATOMIC_RELAXED, __HIP_MEMORY_SCOPE_SYSTEM);
        if (__all(a >= tgt && d >= tgt)) break;
        __builtin_amdgcn_s_sleep(1);
        if (++guard > (1<<18)) bailed = true;  // safety: no deadlock
      }
    }
    __syncthreads();
  }
}

// Build fp16 padded input streams, fp16 classifier weights, zero out[:,0,:].
__global__ void prepass(const float* x, const float* y, const float* W1, const float* W2,
                        f16* xh, f16* dh, f16* W1h, f16* W2h, float* out){
  const size_t NXH = (size_t)TENC*NBAT*KXPAD;
  const size_t NDH = (size_t)TDEC*NBAT*KXPAD;
  const size_t NW1 = 256*512;
  const size_t NW2 = 176*256;
  const size_t NZ  = (size_t)NBAT*DIN;
  const size_t TOTAL = NXH+NDH+NW1+NW2+NZ;
  for (size_t i = (size_t)blockIdx.x*blockDim.x + threadIdx.x; i < TOTAL;
       i += (size_t)gridDim.x*blockDim.x){
    if (i < NXH){
      size_t t = i/(NBAT*KXPAD); size_t r = i%(NBAT*KXPAD);
      size_t bb = r/KXPAD; size_t k = r%KXPAD;
      float v = (t>=1 && k<DIN) ? x[(bb*1024 + (t-1))*DIN + k] : 0.f;
      xh[i] = (f16)v;
    } else if (i < NXH+NDH){
      size_t j = i-NXH;
      size_t t = j/(NBAT*KXPAD); size_t r = j%(NBAT*KXPAD);
      size_t bb = r/KXPAD; size_t k = r%KXPAD;
      float v = (t>=1 && k<DIN) ? y[(bb*1024 + (t-1))*DIN + k] : 0.f;
      dh[j] = (f16)v;
    } else if (i < NXH+NDH+NW1){
      size_t j = i-NXH-NDH; W1h[j] = (f16)W1[j];
    } else if (i < NXH+NDH+NW1+NW2){
      size_t j = i-NXH-NDH-NW1; W2h[j] = (f16)W2[j];
    } else {
      size_t j = i-NXH-NDH-NW1-NW2;
      size_t bb = j/DIN; size_t k = j%DIN;
      out[bb*1024*DIN + k] = 0.f;
    }
  }
}

// Fused classifier: out[b][1+t][:] = relu(hs[t][b]·W1^T + b1)·W2^T + b2
__global__ __launch_bounds__(NT) void cls_kernel(const f16* hs, const f16* W1h, const f16* W2h,
                                                 const float* b1, const float* b2, float* out){
  __shared__ f16 hm[64*264];   // hmid tile, padded stride to dodge bank conflicts
  const int tid = threadIdx.x;
  const int lane = tid & 63, wave = tid >> 6;
  const int kg = lane >> 4, ln = lane & 15;
  const int m0 = blockIdx.x * 64;

  float4v acc[4][4];
  #pragma unroll
  for (int mt=0;mt<4;mt++)
    #pragma unroll
    for (int nt=0;nt<4;nt++) acc[mt][nt] = (float4v){0.f,0.f,0.f,0.f};

  #pragma unroll
  for (int kc=0;kc<16;kc++){
    half8 av[4];
    #pragma unroll
    for (int mt=0;mt<4;mt++)
      av[mt] = *(const half8*)(hs + (size_t)(m0 + mt*16 + ln)*HD + kc*32 + kg*8);
    #pragma unroll
    for (int nt=0;nt<4;nt++){
      half8 bf = *(const half8*)(W1h + (size_t)(wave*64 + nt*16 + ln)*HD + kc*32 + kg*8);
      #pragma unroll
      for (int mt=0;mt<4;mt++) acc[mt][nt] = mfma16(av[mt], bf, acc[mt][nt]);
    }
  }
  #pragma unroll
  for (int nt=0;nt<4;nt++){
    float bv = b1[wave*64 + nt*16 + ln];
    #pragma unroll
    for (int mt=0;mt<4;mt++)
      #pragma unroll
      for (int j=0;j<4;j++){
        float v = acc[mt][nt][j] + bv;
        v = v > 0.f ? v : 0.f;
        hm[(mt*16 + kg*4 + j)*264 + (wave*64 + nt*16 + ln)] = (f16)v;
      }
  }
  __syncthreads();
  for (int nt2 = wave; nt2 < 11; nt2 += 4){
    float4v a2[4];
    #pragma unroll
    for (int mt=0;mt<4;mt++) a2[mt] = (float4v){0.f,0.f,0.f,0.f};
    #pragma unroll
    for (int kc=0;kc<8;kc++){
      half8 bf = *(const half8*)(W2h + (size_t)(nt2*16 + ln)*256 + kc*32 + kg*8);
      #pragma unroll
      for (int mt=0;mt<4;mt++){
        half8 av = *(const half8*)(hm + (size_t)(mt*16 + ln)*264 + kc*32 + kg*8);
        a2[mt] = mfma16(av, bf, a2[mt]);
      }
    }
    float bv = b2[nt2*16 + ln];
    #pragma unroll
    for (int mt=0;mt<4;mt++)
      #pragma unroll
      for (int j=0;j<4;j++){
        int m = m0 + mt*16 + kg*4 + j;
        int bb = m & 63; int t = m >> 6;
        out[((size_t)bb*1024 + 1 + t)*DIN + nt2*16 + ln] = a2[mt][j] + bv;
      }
  }
}

extern "C" void kernel_launch(void* const* d_in, const int* in_sizes, int n_in,
                              void* d_out, int out_size, void* d_ws, size_t ws_size,
                              hipStream_t stream){
  if (ws_size < WS_END) return;  // need ~113 MB scratch
  const float* x = (const float*)d_in[0];
  const float* y = (const float*)d_in[1];

  char* ws = (char*)d_ws;
  u32* cnt = (u32*)(ws + WS_CNT);
  f16* h0  = (f16*)(ws + WS_H0);
  f16* h1  = (f16*)(ws + WS_H1);
  f16* xh  = (f16*)(ws + WS_XH);
  f16* dh  = (f16*)(ws + WS_DH);
  f16* hs  = (f16*)(ws + WS_HS);
  f16* W1h = (f16*)(ws + WS_W1);
  f16* W2h = (f16*)(ws + WS_W2);

  // zero flags + h state buffers
  hipMemsetAsync(ws, 0, WS_ZERO_END, stream);

  prepass<<<4096, NT, 0, stream>>>(x, y, (const float*)d_in[18], (const float*)d_in[20],
                                   xh, dh, W1h, W2h, (float*)d_out);

  Params p;
  p.W_i[0][0] = (const float*)d_in[2];  p.W_h[0][0] = (const float*)d_in[3];
  p.b_i[0][0] = (const float*)d_in[4];  p.b_h[0][0] = (const float*)d_in[5];
  p.W_i[0][1] = (const float*)d_in[6];  p.W_h[0][1] = (const float*)d_in[7];
  p.b_i[0][1] = (const float*)d_in[8];  p.b_h[0][1] = (const float*)d_in[9];
  p.W_i[1][0] = (const float*)d_in[10]; p.W_h[1][0] = (const float*)d_in[11];
  p.b_i[1][0] = (const float*)d_in[12]; p.b_h[1][0] = (const float*)d_in[13];
  p.W_i[1][1] = (const float*)d_in[14]; p.W_h[1][1] = (const float*)d_in[15];
  p.b_i[1][1] = (const float*)d_in[16]; p.b_h[1][1] = (const float*)d_in[17];
  p.xh = xh; p.dh = dh; p.h0 = h0; p.h1 = h1; p.hs = hs; p.cnt = cnt;

  lstm_persistent<<<NB, NT, 0, stream>>>(p);

  cls_kernel<<<TDEC, NT, 0, stream>>>(hs, W1h, W2h,
                                      (const float*)d_in[19], (const float*)d_in[21],
                                      (float*)d_out);
}